// Round 8
// baseline (277.886 us; speedup 1.0000x reference)
//
#include <hip/hip_runtime.h>
#include <hip/hip_fp16.h>

#define NT    2304   // tokens = 48*48
#define DIM   768
#define TD    2304   // 3*dim
#define NHEAD 12
#define HD    64
#define RANK  32
#define KA    832    // augmented K = 768 + 32 (uq) + 32 (uv)
#define NSPLIT 4
#define TILES  9     // 36 / NSPLIT

typedef __attribute__((ext_vector_type(8))) short short8;
typedef __attribute__((ext_vector_type(4))) short short4_t;
typedef __attribute__((ext_vector_type(4))) float floatx4;

__device__ __forceinline__ unsigned short f2bf(float f) {
    union { float f; unsigned u; } v; v.f = f;
    unsigned u = v.u + 0x7FFFu + ((v.u >> 16) & 1u);
    return (unsigned short)(u >> 16);
}
__device__ __forceinline__ float bf2f(unsigned short h) {
    union { unsigned u; float f; } v; v.u = ((unsigned)h) << 16; return v.f;
}
__device__ __forceinline__ void async16(const unsigned short* g, unsigned short* l) {
    __builtin_amdgcn_global_load_lds(
        (const __attribute__((address_space(1))) unsigned int*)g,
        (__attribute__((address_space(3))) unsigned int*)l, 16, 0, 0);
}

// ---------------------------------------------------------------------------
// 64x64 fp32->bf16 transpose tile helper
// ---------------------------------------------------------------------------
__device__ __forceinline__ void tr_tile(const float* __restrict__ src,
                                        unsigned short* __restrict__ dst,
                                        int N, int P, int n0, int k0,
                                        unsigned short* tile, int tid) {
    #pragma unroll
    for (int p = 0; p < 4; ++p) {
        int krow = (tid >> 4) + p * 16, n4 = (tid & 15) * 4;
        float4 v = *(const float4*)(src + (size_t)(k0 + krow) * N + n0 + n4);
        tile[krow * 71 + n4 + 0] = f2bf(v.x);
        tile[krow * 71 + n4 + 1] = f2bf(v.y);
        tile[krow * 71 + n4 + 2] = f2bf(v.z);
        tile[krow * 71 + n4 + 3] = f2bf(v.w);
    }
    __syncthreads();
    #pragma unroll
    for (int p = 0; p < 2; ++p) {
        int c = tid + p * 256;
        int nrow = c >> 3, k8 = (c & 7) * 8;
        short8 o;
        #pragma unroll
        for (int i = 0; i < 8; ++i) o[i] = (short)tile[(k8 + i) * 71 + nrow];
        *(short8*)(dst + (size_t)(n0 + nrow) * P + k0 + k8) = o;
    }
}

// ---------------------------------------------------------------------------
// Fused prep: [0,2304) FacT rows; [2304,2736) Wqkv^T; [2736,2880) Wp^T;
// [2880,2889) Fv fill.
// ---------------------------------------------------------------------------
__global__ __launch_bounds__(256)
void k_prep(const float* __restrict__ x, const float* __restrict__ Fu,
            const float* __restrict__ qF, const float* __restrict__ vF,
            const float* __restrict__ Wqkv, const float* __restrict__ Wp,
            const float* __restrict__ Fv,
            unsigned short* __restrict__ Ax, unsigned short* __restrict__ BqT,
            unsigned short* __restrict__ WpT) {
    __shared__ __align__(16) unsigned short tile[64 * 71];
    int b = blockIdx.x;
    int tid = threadIdx.x;
    if (b < NT) {
        float* part = (float*)tile;            // [8][32]
        float* us = part + 256;                // [32]
        int row = b;
        int r = tid & 31, p = tid >> 5;
        const float* xr = x + (size_t)row * DIM;
        #pragma unroll
        for (int i = 0; i < 3; ++i) {
            int col = tid + i * 256;
            Ax[(size_t)row * KA + col] = f2bf(xr[col]);
        }
        float acc = 0.f;
        int k0 = p * (DIM / 8);
        for (int k = k0; k < k0 + DIM / 8; ++k)
            acc = fmaf(xr[k], Fu[k * RANK + r], acc);
        part[p * 32 + r] = acc;
        __syncthreads();
        if (tid < 32) {
            float s = 0.f;
            #pragma unroll
            for (int pp = 0; pp < 8; ++pp) s += part[pp * 32 + tid];
            us[tid] = s;
        }
        __syncthreads();
        if (tid < 64) {
            int c = tid & 31;
            const float* F = (tid < 32) ? qF : vF;
            float s = 0.f;
            #pragma unroll
            for (int rr = 0; rr < RANK; ++rr) s = fmaf(us[rr], F[rr * RANK + c], s);
            int col = (tid < 32) ? (768 + c) : (800 + c);
            Ax[(size_t)row * KA + col] = f2bf(s);
        }
    } else if (b < NT + 432) {
        int i = b - NT;
        tr_tile(Wqkv, BqT, TD, KA, (i % 36) * 64, (i / 36) * 64, tile, tid);
    } else if (b < NT + 576) {
        int i = b - NT - 432;
        tr_tile(Wp, WpT, DIM, DIM, (i % 12) * 64, (i / 12) * 64, tile, tid);
    } else {
        int i = b - NT - 576;
        int n = i * 256 + tid;
        unsigned short* d = BqT + (size_t)n * KA;
        #pragma unroll 4
        for (int r = 0; r < 32; ++r) {
            d[768 + r] = (n < 768)   ? f2bf(Fv[r * 768 + n])          : (unsigned short)0;
            d[800 + r] = (n >= 1536) ? f2bf(Fv[r * 768 + (n - 1536)]) : (unsigned short)0;
        }
    }
}

// ---------------------------------------------------------------------------
// bf16 MFMA GEMM, BM=64, BN in {64,128}: C = A @ BT^T + bias. BK=64.
// LDS packed [row][64] with XOR-8 group swizzle (2-way conflict-free),
// global_load_lds(16B) staging, half the barriers of BK=32.
// FUSEV: cols >=1536 also written transposed into VtG[chan][token].
// ---------------------------------------------------------------------------
template<int BN, int OUTF, int FUSEV>
__global__ __launch_bounds__(256)
void k_gemm64(const unsigned short* __restrict__ A,
              const unsigned short* __restrict__ BT,
              const float* __restrict__ bias, void* __restrict__ Cout,
              int N, int K, unsigned short* __restrict__ VtG) {
    __shared__ __align__(16) unsigned short As[64 * 64];
    __shared__ __align__(16) unsigned short Bs[BN * 64];
    constexpr int NJ = BN / 32;
    int tid = threadIdx.x;
    int m0 = blockIdx.y * 64, n0 = blockIdx.x * BN;
    int lane = tid & 63, wave = tid >> 6;
    int wr = wave >> 1, wc = wave & 1;
    int lm = lane & 15, quad = lane >> 4;

    int srow = tid >> 3;                         // 0..31
    int sgrp = ((tid & 7) ^ (srow & 7)) * 8;     // swizzled k-group (global src)
    const unsigned short* gA0 = A + (size_t)(m0 + srow) * K + sgrp;
    const unsigned short* gA1 = A + (size_t)(m0 + 32 + srow) * K + sgrp;
    const unsigned short* gB0 = BT + (size_t)(n0 + srow) * K + sgrp;
    const unsigned short* gB1 = BT + (size_t)(n0 + 32 + srow) * K + sgrp;
    unsigned short* lA0 = As + wave * 512;       // wave-uniform bases
    unsigned short* lA1 = As + 2048 + wave * 512;
    unsigned short* lB0 = Bs + wave * 512;
    unsigned short* lB1 = Bs + 2048 + wave * 512;

    floatx4 acc[2][NJ];
    #pragma unroll
    for (int i = 0; i < 2; ++i)
        #pragma unroll
        for (int j = 0; j < NJ; ++j) acc[i][j] = (floatx4){0.f, 0.f, 0.f, 0.f};

    for (int kt = 0; kt < K; kt += 64) {
        async16(gA0 + kt, lA0);
        async16(gA1 + kt, lA1);
        async16(gB0 + kt, lB0);
        async16(gB1 + kt, lB1);
        if constexpr (BN == 128) {
            const unsigned short* gB2 = BT + (size_t)(n0 + 64 + srow) * K + sgrp;
            const unsigned short* gB3 = BT + (size_t)(n0 + 96 + srow) * K + sgrp;
            async16(gB2 + kt, Bs + 4096 + wave * 512);
            async16(gB3 + kt, Bs + 6144 + wave * 512);
        }
        __syncthreads();
        #pragma unroll
        for (int kk = 0; kk < 2; ++kk) {
            short8 af[2];
            #pragma unroll
            for (int t2 = 0; t2 < 2; ++t2) {
                int row = wr * 32 + t2 * 16 + lm;
                int g = kk * 4 + quad;
                af[t2] = *(const short8*)(As + row * 64 + ((g ^ (row & 7)) * 8));
            }
            #pragma unroll
            for (int j = 0; j < NJ; ++j) {
                int row = wc * (BN / 2) + j * 16 + lm;
                int g = kk * 4 + quad;
                short8 bq = *(const short8*)(Bs + row * 64 + ((g ^ (row & 7)) * 8));
                acc[0][j] = __builtin_amdgcn_mfma_f32_16x16x32_bf16(af[0], bq, acc[0][j], 0, 0, 0);
                acc[1][j] = __builtin_amdgcn_mfma_f32_16x16x32_bf16(af[1], bq, acc[1][j], 0, 0, 0);
            }
        }
        __syncthreads();
    }

    #pragma unroll
    for (int jt = 0; jt < NJ; ++jt) {
        int col = n0 + wc * (BN / 2) + jt * 16 + lm;
        float bv = bias[col];
        #pragma unroll
        for (int it = 0; it < 2; ++it) {
            int rowb = m0 + wr * 32 + it * 16 + quad * 4;
            #pragma unroll
            for (int r = 0; r < 4; ++r) {
                float val = acc[it][jt][r] + bv;
                if (OUTF)
                    ((float*)Cout)[(size_t)(rowb + r) * N + col] = val;
                else
                    ((unsigned short*)Cout)[(size_t)(rowb + r) * N + col] = f2bf(val);
            }
            if (FUSEV && col >= 1536) {
                short4_t vt;
                #pragma unroll
                for (int r = 0; r < 4; ++r) vt[r] = (short)f2bf(acc[it][jt][r] + bv);
                *(short4_t*)(VtG + (size_t)(col - 1536) * NT + rowb) = vt;
            }
        }
    }
}

// ---------------------------------------------------------------------------
// Rel-pos bias tables (half, pre-multiplied by log2(e))
// ---------------------------------------------------------------------------
__global__ __launch_bounds__(256)
void k_bias(const unsigned short* __restrict__ qkv, const float* __restrict__ rph,
            const float* __restrict__ rpw, unsigned short* __restrict__ BhG,
            unsigned short* __restrict__ BwG) {
    __shared__ float Qf[48 * 68];
    __shared__ float Ts[48 * 68];
    int tid = threadIdx.x;
    int pos = blockIdx.x, h = blockIdx.y, which = blockIdx.z;
    const float* tab = which ? rpw : rph;
    for (int idx = tid; idx < 48 * 8; idx += 256) {
        int row = idx >> 3, c8 = (idx & 7) * 8;
        int t = which ? (row * 48 + pos) : (pos * 48 + row);
        short8 q8 = *(const short8*)(qkv + (size_t)t * TD + h * HD + c8);
        #pragma unroll
        for (int i = 0; i < 8; ++i) Qf[row * 68 + c8 + i] = bf2f((unsigned short)q8[i]);
    }
    for (int idx = tid; idx < 48 * 16; idx += 256) {
        int row = idx >> 4, c4 = (idx & 15) * 4;
        float4 v = *(const float4*)(tab + (size_t)(pos + row) * HD + c4);
        Ts[row * 68 + c4 + 0] = v.x;
        Ts[row * 68 + c4 + 1] = v.y;
        Ts[row * 68 + c4 + 2] = v.z;
        Ts[row * 68 + c4 + 3] = v.w;
    }
    __syncthreads();
    unsigned short* dst = which ? BwG : BhG;
    for (int idx = tid; idx < 48 * 48; idx += 256) {
        int r = idx / 48, j = idx - r * 48;
        const float* qr = Qf + r * 68;
        const float* tr = Ts + (47 - j) * 68;
        float s = 0.f;
        #pragma unroll
        for (int c = 0; c < 16; ++c) {
            float4 a = *(const float4*)(qr + c * 4);
            float4 b = *(const float4*)(tr + c * 4);
            s = fmaf(a.x, b.x, s); s = fmaf(a.y, b.y, s);
            s = fmaf(a.z, b.z, s); s = fmaf(a.w, b.w, s);
        }
        int t = which ? (r * 48 + pos) : (pos * 48 + r);
        __half hh = __float2half(s * 1.44269504f);
        dst[(size_t)(h * 48 + j) * NT + t] = *(unsigned short*)&hh;
    }
}

// ---------------------------------------------------------------------------
// MFMA flash attention, 4-way key split, BARRIER-FREE K-loop:
// K/V fragments loaded directly from global (L1/L2-served); the P round-trip
// through LDS is wave-private (wave w touches only rows w*16..w*16+15, the
// same rows its Q fragments came from), so no __syncthreads after Q-stage.
// ---------------------------------------------------------------------------
__global__ __launch_bounds__(256)
void k_attn(const unsigned short* __restrict__ qkv,
            const unsigned short* __restrict__ VtG,
            const unsigned short* __restrict__ BhG,
            const unsigned short* __restrict__ BwG,
            unsigned short* __restrict__ Opart, float* __restrict__ Lpart) {
    __shared__ __align__(16) unsigned short Ps[64 * 72];   // Q stage, then P
    __shared__ __align__(16) unsigned short BhS[48 * 68];  // half*log2e [j][row]
    __shared__ __align__(16) unsigned short BwS[48 * 68];

    int tid = threadIdx.x;
    int lane = tid & 63, wave = tid >> 6;
    int lm = lane & 15, quad = lane >> 4;
    int i0 = blockIdx.x * 64, h = blockIdx.y, z = blockIdx.z;

    int row0 = tid >> 3, cc0 = (tid & 7) * 8;

    // ---- stage Q into Ps + bias tables ----
    *(short8*)(Ps + row0 * 72 + cc0) =
        *(const short8*)(qkv + (size_t)(i0 + row0) * TD + h * HD + cc0);
    *(short8*)(Ps + (row0 + 32) * 72 + cc0) =
        *(const short8*)(qkv + (size_t)(i0 + row0 + 32) * TD + h * HD + cc0);
    for (int idx = tid; idx < 48 * 16; idx += 256) {
        int j = idx >> 4, r4 = (idx & 15) * 4;
        *(short4_t*)(BhS + j * 68 + r4) =
            *(const short4_t*)(BhG + (size_t)(h * 48 + j) * NT + i0 + r4);
        *(short4_t*)(BwS + j * 68 + r4) =
            *(const short4_t*)(BwG + (size_t)(h * 48 + j) * NT + i0 + r4);
    }
    __syncthreads();   // the ONLY barrier

    short8 qf[2];
    qf[0] = *(const short8*)(Ps + (wave * 16 + lm) * 72 + quad * 8);
    qf[1] = *(const short8*)(Ps + (wave * 16 + lm) * 72 + 32 + quad * 8);

    const unsigned short* kb = qkv + 768 + h * HD;
    const unsigned short* vb = VtG + (size_t)h * HD * NT;

    floatx4 o_acc[4];
    float lp4[4] = {0.f, 0.f, 0.f, 0.f};
    #pragma unroll
    for (int nt = 0; nt < 4; ++nt) o_acc[nt] = (floatx4){0.f, 0.f, 0.f, 0.f};

    int j0 = z * TILES * 64;
    int r0 = wave * 16 + quad * 4;

    for (int t = 0; t < TILES; ++t) {
        int jb = j0 + t * 64;

        // S = Q K^T, K-frags direct from global
        floatx4 s_acc[4];
        #pragma unroll
        for (int nt = 0; nt < 4; ++nt) s_acc[nt] = (floatx4){0.f, 0.f, 0.f, 0.f};
        #pragma unroll
        for (int kt = 0; kt < 2; ++kt)
            #pragma unroll
            for (int nt = 0; nt < 4; ++nt) {
                short8 kf = *(const short8*)(kb + (size_t)(jb + nt * 16 + lm) * TD
                                             + kt * 32 + quad * 8);
                s_acc[nt] = __builtin_amdgcn_mfma_f32_16x16x32_bf16(
                    qf[kt], kf, s_acc[nt], 0, 0, 0);
            }

        // epilogue: bias (packed half adds) + exp2 -> Ps (wave-private rows)
        #pragma unroll
        for (int nt = 0; nt < 4; ++nt) {
            int jg = jb + nt * 16 + lm;
            int hj = jg / 48, wj = jg - hj * 48;
            union { short4_t s; __half2 h[2]; } ub, uw;
            ub.s = *(const short4_t*)(BhS + hj * 68 + r0);
            uw.s = *(const short4_t*)(BwS + wj * 68 + r0);
            __half2 s01 = __hadd2(ub.h[0], uw.h[0]);
            __half2 s23 = __hadd2(ub.h[1], uw.h[1]);
            float2 f01 = __half22float2(s01);
            float2 f23 = __half22float2(s23);
            float bb[4] = {f01.x, f01.y, f23.x, f23.y};
            #pragma unroll
            for (int r = 0; r < 4; ++r) {
                float pe = exp2f(fmaf(0.18033688f, s_acc[nt][r], bb[r]));
                lp4[r] += pe;
                Ps[(r0 + r) * 72 + nt * 16 + lm] = f2bf(pe);
            }
        }

        // O += P V : P from wave-private LDS rows, V-frags direct from global
        #pragma unroll
        for (int kt = 0; kt < 2; ++kt) {
            short8 pf = *(const short8*)(Ps + (wave * 16 + lm) * 72 + kt * 32 + quad * 8);
            #pragma unroll
            for (int nt = 0; nt < 4; ++nt) {
                short8 vf = *(const short8*)(vb + (size_t)(nt * 16 + lm) * NT
                                             + jb + kt * 32 + quad * 8);
                o_acc[nt] = __builtin_amdgcn_mfma_f32_16x16x32_bf16(
                    pf, vf, o_acc[nt], 0, 0, 0);
            }
        }
    }

    // partial row sums
    #pragma unroll
    for (int r = 0; r < 4; ++r) {
        float s = lp4[r];
        s += __shfl_xor(s, 1, 16);
        s += __shfl_xor(s, 2, 16);
        s += __shfl_xor(s, 4, 16);
        s += __shfl_xor(s, 8, 16);
        if (lm == 0)
            Lpart[((size_t)z * NHEAD + h) * NT + i0 + wave * 16 + quad * 4 + r] = s;
    }
    unsigned short* op = Opart + (size_t)z * NT * DIM;
    #pragma unroll
    for (int nt = 0; nt < 4; ++nt)
        #pragma unroll
        for (int r = 0; r < 4; ++r)
            op[(size_t)(i0 + wave * 16 + quad * 4 + r) * DIM + h * HD + nt * 16 + lm]
                = f2bf(o_acc[nt][r]);
}

// ---------------------------------------------------------------------------
// Combine splits
// ---------------------------------------------------------------------------
__global__ __launch_bounds__(256)
void k_comb(const unsigned short* __restrict__ Opart, const float* __restrict__ Lpart,
            unsigned short* __restrict__ aob) {
    int gid = blockIdx.x * 256 + threadIdx.x;
    int t = gid / 96, c8 = (gid - t * 96) * 8;
    int h = c8 >> 6;
    float l = 0.f;
    #pragma unroll
    for (int s = 0; s < NSPLIT; ++s)
        l += Lpart[((size_t)s * NHEAD + h) * NT + t];
    float inv = 1.f / l;
    float acc[8] = {0, 0, 0, 0, 0, 0, 0, 0};
    #pragma unroll
    for (int s = 0; s < NSPLIT; ++s) {
        short8 v = *(const short8*)(Opart + (size_t)s * NT * DIM + (size_t)t * DIM + c8);
        #pragma unroll
        for (int i = 0; i < 8; ++i) acc[i] += bf2f((unsigned short)v[i]);
    }
    short8 o;
    #pragma unroll
    for (int i = 0; i < 8; ++i) o[i] = (short)f2bf(acc[i] * inv);
    *(short8*)(aob + (size_t)t * DIM + c8) = o;
}

// ---------------------------------------------------------------------------
extern "C" void kernel_launch(void* const* d_in, const int* in_sizes, int n_in,
                              void* d_out, int out_size, void* d_ws, size_t ws_size,
                              hipStream_t stream) {
    const float* x    = (const float*)d_in[0];
    const float* Wqkv = (const float*)d_in[1];
    const float* bqkv = (const float*)d_in[2];
    const float* Fu   = (const float*)d_in[3];
    const float* Fv   = (const float*)d_in[4];
    const float* qF   = (const float*)d_in[5];
    const float* vF   = (const float*)d_in[6];
    const float* rph  = (const float*)d_in[7];
    const float* rpw  = (const float*)d_in[8];
    const float* Wp   = (const float*)d_in[9];
    const float* bp   = (const float*)d_in[10];

    unsigned short* ws   = (unsigned short*)d_ws;
    unsigned short* qkvb = ws;                               // [2304][2304]
    unsigned short* aob  = qkvb;                             // alias: qkvb dead post-attn
    unsigned short* WpT  = qkvb + (size_t)NT * TD;           // [768][768]
    unsigned short* VtG  = WpT  + (size_t)DIM * DIM;         // [768][2304]
    unsigned short* BhG  = VtG  + (size_t)DIM * NT;          // [12][48][2304] half
    unsigned short* BwG  = BhG  + (size_t)NHEAD * 48 * NT;
    float*          Lpart = (float*)(BwG + (size_t)NHEAD * 48 * NT); // [4][12][2304]
    unsigned short* tail = (unsigned short*)(Lpart + (size_t)NSPLIT * NHEAD * NT);
    unsigned short* Ax   = tail;                             // [2304][832] (early)
    unsigned short* BqT  = Ax + (size_t)NT * KA;             // [2304][832] (early)
    unsigned short* Opart = tail;                            // [4][2304][768] (late)

    hipLaunchKernelGGL(k_prep, dim3(NT + 576 + 9), dim3(256), 0, stream,
                       x, Fu, qF, vF, Wqkv, Wp, Fv, Ax, BqT, WpT);
    hipLaunchKernelGGL((k_gemm64<128, 0, 1>), dim3(TD / 128, NT / 64), dim3(256), 0,
                       stream, Ax, BqT, bqkv, (void*)qkvb, TD, KA, VtG);
    hipLaunchKernelGGL(k_bias, dim3(48, NHEAD, 2), dim3(256), 0, stream,
                       qkvb, rph, rpw, BhG, BwG);
    hipLaunchKernelGGL(k_attn, dim3(NT / 64, NHEAD, NSPLIT), dim3(256), 0, stream,
                       qkvb, VtG, BhG, BwG, Opart, Lpart);
    hipLaunchKernelGGL(k_comb, dim3(NT * 96 / 256), dim3(256), 0, stream,
                       Opart, Lpart, aob);
    hipLaunchKernelGGL((k_gemm64<64, 1, 0>), dim3(DIM / 64, NT / 64), dim3(256), 0,
                       stream, aob, WpT, bp, d_out, DIM, DIM, (unsigned short*)nullptr);
}

// Round 9
// 203.702 us; speedup vs baseline: 1.3642x; 1.3642x over previous
//
#include <hip/hip_runtime.h>
#include <hip/hip_fp16.h>

#define NT    2304   // tokens = 48*48
#define DIM   768
#define TD    2304   // 3*dim
#define NHEAD 12
#define HD    64
#define RANK  32
#define KA    832    // augmented K = 768 + 32 (uq) + 32 (uv)
#define NSPLIT 4
#define TILES  9     // 36 / NSPLIT

typedef __attribute__((ext_vector_type(8))) short short8;
typedef __attribute__((ext_vector_type(4))) short short4_t;
typedef __attribute__((ext_vector_type(4))) float floatx4;

__device__ __forceinline__ unsigned short f2bf(float f) {
    union { float f; unsigned u; } v; v.f = f;
    unsigned u = v.u + 0x7FFFu + ((v.u >> 16) & 1u);
    return (unsigned short)(u >> 16);
}
__device__ __forceinline__ float bf2f(unsigned short h) {
    union { unsigned u; float f; } v; v.u = ((unsigned)h) << 16; return v.f;
}
__device__ __forceinline__ float h2f(unsigned short u) {
    __half h = *(__half*)&u; return __half2float(h);
}
__device__ __forceinline__ void async16(const unsigned short* g, unsigned short* l) {
    __builtin_amdgcn_global_load_lds(
        (const __attribute__((address_space(1))) unsigned int*)g,
        (__attribute__((address_space(3))) unsigned int*)l, 16, 0, 0);
}

// ---------------------------------------------------------------------------
// 64x64 fp32->bf16 transpose tile helper
// ---------------------------------------------------------------------------
__device__ __forceinline__ void tr_tile(const float* __restrict__ src,
                                        unsigned short* __restrict__ dst,
                                        int N, int P, int n0, int k0,
                                        unsigned short* tile, int tid) {
    #pragma unroll
    for (int p = 0; p < 4; ++p) {
        int krow = (tid >> 4) + p * 16, n4 = (tid & 15) * 4;
        float4 v = *(const float4*)(src + (size_t)(k0 + krow) * N + n0 + n4);
        tile[krow * 71 + n4 + 0] = f2bf(v.x);
        tile[krow * 71 + n4 + 1] = f2bf(v.y);
        tile[krow * 71 + n4 + 2] = f2bf(v.z);
        tile[krow * 71 + n4 + 3] = f2bf(v.w);
    }
    __syncthreads();
    #pragma unroll
    for (int p = 0; p < 2; ++p) {
        int c = tid + p * 256;
        int nrow = c >> 3, k8 = (c & 7) * 8;
        short8 o;
        #pragma unroll
        for (int i = 0; i < 8; ++i) o[i] = (short)tile[(k8 + i) * 71 + nrow];
        *(short8*)(dst + (size_t)(n0 + nrow) * P + k0 + k8) = o;
    }
}

// ---------------------------------------------------------------------------
// Fused prep: [0,2304) FacT rows; [2304,2736) Wqkv^T; [2736,2880) Wp^T;
// [2880,2889) Fv fill.
// ---------------------------------------------------------------------------
__global__ __launch_bounds__(256)
void k_prep(const float* __restrict__ x, const float* __restrict__ Fu,
            const float* __restrict__ qF, const float* __restrict__ vF,
            const float* __restrict__ Wqkv, const float* __restrict__ Wp,
            const float* __restrict__ Fv,
            unsigned short* __restrict__ Ax, unsigned short* __restrict__ BqT,
            unsigned short* __restrict__ WpT) {
    __shared__ __align__(16) unsigned short tile[64 * 71];
    int b = blockIdx.x;
    int tid = threadIdx.x;
    if (b < NT) {
        float* part = (float*)tile;            // [8][32]
        float* us = part + 256;                // [32]
        int row = b;
        int r = tid & 31, p = tid >> 5;
        const float* xr = x + (size_t)row * DIM;
        if (tid < 96) {                        // vectorized bf16 cast of x row
            const float4* pp = (const float4*)(xr + tid * 8);
            float4 a = pp[0], bb = pp[1];
            short8 o;
            o[0] = (short)f2bf(a.x);  o[1] = (short)f2bf(a.y);
            o[2] = (short)f2bf(a.z);  o[3] = (short)f2bf(a.w);
            o[4] = (short)f2bf(bb.x); o[5] = (short)f2bf(bb.y);
            o[6] = (short)f2bf(bb.z); o[7] = (short)f2bf(bb.w);
            *(short8*)(Ax + (size_t)row * KA + tid * 8) = o;
        }
        float acc = 0.f;
        int k0 = p * (DIM / 8);
        for (int k = k0; k < k0 + DIM / 8; ++k)
            acc = fmaf(xr[k], Fu[k * RANK + r], acc);
        part[p * 32 + r] = acc;
        __syncthreads();
        if (tid < 32) {
            float s = 0.f;
            #pragma unroll
            for (int pp2 = 0; pp2 < 8; ++pp2) s += part[pp2 * 32 + tid];
            us[tid] = s;
        }
        __syncthreads();
        if (tid < 64) {
            int c = tid & 31;
            const float* F = (tid < 32) ? qF : vF;
            float s = 0.f;
            #pragma unroll
            for (int rr = 0; rr < RANK; ++rr) s = fmaf(us[rr], F[rr * RANK + c], s);
            int col = (tid < 32) ? (768 + c) : (800 + c);
            Ax[(size_t)row * KA + col] = f2bf(s);
        }
    } else if (b < NT + 432) {
        int i = b - NT;
        tr_tile(Wqkv, BqT, TD, KA, (i % 36) * 64, (i / 36) * 64, tile, tid);
    } else if (b < NT + 576) {
        int i = b - NT - 432;
        tr_tile(Wp, WpT, DIM, DIM, (i % 12) * 64, (i / 12) * 64, tile, tid);
    } else {
        int i = b - NT - 576;
        int n = i * 256 + tid;
        unsigned short* d = BqT + (size_t)n * KA;
        #pragma unroll 4
        for (int r = 0; r < 32; ++r) {
            d[768 + r] = (n < 768)   ? f2bf(Fv[r * 768 + n])          : (unsigned short)0;
            d[800 + r] = (n >= 1536) ? f2bf(Fv[r * 768 + (n - 1536)]) : (unsigned short)0;
        }
    }
}

// ---------------------------------------------------------------------------
// bf16 MFMA GEMM, BM=64, BN in {64,128}: C = A @ BT^T + bias. BK=64.
// global_load_lds(16B) staging, XOR-8 swizzle on the global source.
// FUSEV: cols >=1536 also written transposed into VtG[chan][token].
// ---------------------------------------------------------------------------
template<int BN, int OUTF, int FUSEV>
__global__ __launch_bounds__(256)
void k_gemm64(const unsigned short* __restrict__ A,
              const unsigned short* __restrict__ BT,
              const float* __restrict__ bias, void* __restrict__ Cout,
              int N, int K, unsigned short* __restrict__ VtG) {
    __shared__ __align__(16) unsigned short As[64 * 64];
    __shared__ __align__(16) unsigned short Bs[BN * 64];
    constexpr int NJ = BN / 32;
    int tid = threadIdx.x;
    int m0 = blockIdx.y * 64, n0 = blockIdx.x * BN;
    int lane = tid & 63, wave = tid >> 6;
    int wr = wave >> 1, wc = wave & 1;
    int lm = lane & 15, quad = lane >> 4;

    int srow = tid >> 3;                         // 0..31
    int sgrp = ((tid & 7) ^ (srow & 7)) * 8;     // swizzled k-group (global src)
    const unsigned short* gA0 = A + (size_t)(m0 + srow) * K + sgrp;
    const unsigned short* gA1 = A + (size_t)(m0 + 32 + srow) * K + sgrp;
    const unsigned short* gB0 = BT + (size_t)(n0 + srow) * K + sgrp;
    const unsigned short* gB1 = BT + (size_t)(n0 + 32 + srow) * K + sgrp;
    unsigned short* lA0 = As + wave * 512;       // wave-uniform bases
    unsigned short* lA1 = As + 2048 + wave * 512;
    unsigned short* lB0 = Bs + wave * 512;
    unsigned short* lB1 = Bs + 2048 + wave * 512;

    floatx4 acc[2][NJ];
    #pragma unroll
    for (int i = 0; i < 2; ++i)
        #pragma unroll
        for (int j = 0; j < NJ; ++j) acc[i][j] = (floatx4){0.f, 0.f, 0.f, 0.f};

    for (int kt = 0; kt < K; kt += 64) {
        async16(gA0 + kt, lA0);
        async16(gA1 + kt, lA1);
        async16(gB0 + kt, lB0);
        async16(gB1 + kt, lB1);
        if constexpr (BN == 128) {
            const unsigned short* gB2 = BT + (size_t)(n0 + 64 + srow) * K + sgrp;
            const unsigned short* gB3 = BT + (size_t)(n0 + 96 + srow) * K + sgrp;
            async16(gB2 + kt, Bs + 4096 + wave * 512);
            async16(gB3 + kt, Bs + 6144 + wave * 512);
        }
        __syncthreads();
        #pragma unroll
        for (int kk = 0; kk < 2; ++kk) {
            short8 af[2];
            #pragma unroll
            for (int t2 = 0; t2 < 2; ++t2) {
                int row = wr * 32 + t2 * 16 + lm;
                int g = kk * 4 + quad;
                af[t2] = *(const short8*)(As + row * 64 + ((g ^ (row & 7)) * 8));
            }
            #pragma unroll
            for (int j = 0; j < NJ; ++j) {
                int row = wc * (BN / 2) + j * 16 + lm;
                int g = kk * 4 + quad;
                short8 bq = *(const short8*)(Bs + row * 64 + ((g ^ (row & 7)) * 8));
                acc[0][j] = __builtin_amdgcn_mfma_f32_16x16x32_bf16(af[0], bq, acc[0][j], 0, 0, 0);
                acc[1][j] = __builtin_amdgcn_mfma_f32_16x16x32_bf16(af[1], bq, acc[1][j], 0, 0, 0);
            }
        }
        __syncthreads();
    }

    #pragma unroll
    for (int jt = 0; jt < NJ; ++jt) {
        int col = n0 + wc * (BN / 2) + jt * 16 + lm;
        float bv = bias[col];
        #pragma unroll
        for (int it = 0; it < 2; ++it) {
            int rowb = m0 + wr * 32 + it * 16 + quad * 4;
            #pragma unroll
            for (int r = 0; r < 4; ++r) {
                float val = acc[it][jt][r] + bv;
                if (OUTF)
                    ((float*)Cout)[(size_t)(rowb + r) * N + col] = val;
                else
                    ((unsigned short*)Cout)[(size_t)(rowb + r) * N + col] = f2bf(val);
            }
            if (FUSEV && col >= 1536) {
                short4_t vt;
                #pragma unroll
                for (int r = 0; r < 4; ++r) vt[r] = (short)f2bf(acc[it][jt][r] + bv);
                *(short4_t*)(VtG + (size_t)(col - 1536) * NT + rowb) = vt;
            }
        }
    }
}

// ---------------------------------------------------------------------------
// Rel-pos bias tables via MFMA: Bh = q(48x64) @ T^T, T[j][c]=tab[pos+47-j][c].
// Stored as half, pre-multiplied by log2(e). block=(pos, h, which).
// ---------------------------------------------------------------------------
__global__ __launch_bounds__(256)
void k_bias(const unsigned short* __restrict__ qkv, const float* __restrict__ rph,
            const float* __restrict__ rpw, unsigned short* __restrict__ BhG,
            unsigned short* __restrict__ BwG) {
    __shared__ __align__(16) unsigned short Qs[48 * 68];
    __shared__ __align__(16) unsigned short Ts[48 * 68];
    int tid = threadIdx.x;
    int pos = blockIdx.x, h = blockIdx.y, which = blockIdx.z;
    const float* tab = which ? rpw : rph;
    // stage q rows (already bf16)
    for (int idx = tid; idx < 48 * 8; idx += 256) {
        int row = idx >> 3, c8 = (idx & 7) * 8;
        int t = which ? (row * 48 + pos) : (pos * 48 + row);
        *(short8*)(Qs + row * 68 + c8) =
            *(const short8*)(qkv + (size_t)t * TD + h * HD + c8);
    }
    // stage T[j][c] = tab[pos+47-j][c] as bf16
    for (int idx = tid; idx < 48 * 8; idx += 256) {
        int j = idx >> 3, c8 = (idx & 7) * 8;
        const float* src = tab + (size_t)(pos + 47 - j) * HD + c8;
        short8 o;
        #pragma unroll
        for (int i = 0; i < 8; ++i) o[i] = (short)f2bf(src[i]);
        *(short8*)(Ts + j * 68 + c8) = o;
    }
    __syncthreads();
    int lane = tid & 63, wave = tid >> 6;
    int lm = lane & 15, quad = lane >> 4;
    unsigned short* dst = which ? BwG : BhG;
    for (int tt = wave; tt < 9; tt += 4) {
        int rt = tt / 3, jt = tt - rt * 3;
        floatx4 acc = (floatx4){0.f, 0.f, 0.f, 0.f};
        #pragma unroll
        for (int kt = 0; kt < 2; ++kt) {
            short8 a = *(const short8*)(Qs + (rt * 16 + lm) * 68 + kt * 32 + quad * 8);
            short8 bb = *(const short8*)(Ts + (jt * 16 + lm) * 68 + kt * 32 + quad * 8);
            acc = __builtin_amdgcn_mfma_f32_16x16x32_bf16(a, bb, acc, 0, 0, 0);
        }
        int j = jt * 16 + lm;
        int r0 = rt * 16 + quad * 4;
        if (which == 0) {
            short4_t o;
            #pragma unroll
            for (int r = 0; r < 4; ++r) {
                __half hh = __float2half(acc[r] * 1.44269504f);
                o[r] = *(short*)&hh;
            }
            *(short4_t*)(dst + (size_t)(h * 48 + j) * NT + pos * 48 + r0) = o;
        } else {
            #pragma unroll
            for (int r = 0; r < 4; ++r) {
                __half hh = __float2half(acc[r] * 1.44269504f);
                dst[(size_t)(h * 48 + j) * NT + (size_t)(r0 + r) * 48 + pos] =
                    *(unsigned short*)&hh;
            }
        }
    }
}

// ---------------------------------------------------------------------------
// MFMA flash attention, 4-way key split, register-prefetch pipeline,
// 2 barriers per K-tile (P round-trip is intra-wave) — R7-proven version.
// ---------------------------------------------------------------------------
__global__ __launch_bounds__(256)
void k_attn(const unsigned short* __restrict__ qkv,
            const unsigned short* __restrict__ VtG,
            const unsigned short* __restrict__ BhG,
            const unsigned short* __restrict__ BwG,
            unsigned short* __restrict__ Opart, float* __restrict__ Lpart) {
    __shared__ __align__(16) unsigned short Ks[64 * 72];
    __shared__ __align__(16) unsigned short Vts[64 * 72];
    __shared__ __align__(16) unsigned short Ps[64 * 72];
    __shared__ unsigned short BhS[48 * 68];
    __shared__ unsigned short BwS[48 * 68];

    int tid = threadIdx.x;
    int lane = tid & 63, wave = tid >> 6;
    int lm = lane & 15, quad = lane >> 4;
    int i0 = blockIdx.x * 64, h = blockIdx.y, z = blockIdx.z;

    int row0 = tid >> 3, cc0 = (tid & 7) * 8;
    int row1 = row0 + 32, cc1 = cc0;

    *(short8*)(Ps + row0 * 72 + cc0) =
        *(const short8*)(qkv + (size_t)(i0 + row0) * TD + h * HD + cc0);
    *(short8*)(Ps + row1 * 72 + cc1) =
        *(const short8*)(qkv + (size_t)(i0 + row1) * TD + h * HD + cc1);
    __syncthreads();
    short8 qf[2];
    qf[0] = *(const short8*)(Ps + (wave * 16 + lm) * 72 + quad * 8);
    qf[1] = *(const short8*)(Ps + (wave * 16 + lm) * 72 + 32 + quad * 8);

    for (int idx = tid; idx < 48 * 16; idx += 256) {
        int j = idx >> 4, r4 = (idx & 15) * 4;
        *(short4_t*)(BhS + j * 68 + r4) =
            *(const short4_t*)(BhG + (size_t)(h * 48 + j) * NT + i0 + r4);
        *(short4_t*)(BwS + j * 68 + r4) =
            *(const short4_t*)(BwG + (size_t)(h * 48 + j) * NT + i0 + r4);
    }

    int j0 = z * TILES * 64;
    short8 kr0 = *(const short8*)(qkv + (size_t)(j0 + row0) * TD + 768 + h * HD + cc0);
    short8 kr1 = *(const short8*)(qkv + (size_t)(j0 + row1) * TD + 768 + h * HD + cc1);
    short8 vr0 = *(const short8*)(VtG + (size_t)(h * HD + row0) * NT + j0 + cc0);
    short8 vr1 = *(const short8*)(VtG + (size_t)(h * HD + row1) * NT + j0 + cc1);

    floatx4 o_acc[4];
    float lp4[4] = {0.f, 0.f, 0.f, 0.f};
    #pragma unroll
    for (int nt = 0; nt < 4; ++nt) o_acc[nt] = (floatx4){0.f, 0.f, 0.f, 0.f};

    for (int t = 0; t < TILES; ++t) {
        int jb = j0 + t * 64;
        *(short8*)(Ks + row0 * 72 + cc0) = kr0;
        *(short8*)(Ks + row1 * 72 + cc1) = kr1;
        *(short8*)(Vts + row0 * 72 + cc0) = vr0;
        *(short8*)(Vts + row1 * 72 + cc1) = vr1;
        __syncthreads();

        floatx4 s_acc[4];
        #pragma unroll
        for (int nt = 0; nt < 4; ++nt) s_acc[nt] = (floatx4){0.f, 0.f, 0.f, 0.f};
        #pragma unroll
        for (int kt = 0; kt < 2; ++kt)
            #pragma unroll
            for (int nt = 0; nt < 4; ++nt) {
                short8 kf = *(const short8*)(Ks + (nt * 16 + lm) * 72 + kt * 32 + quad * 8);
                s_acc[nt] = __builtin_amdgcn_mfma_f32_16x16x32_bf16(
                    qf[kt], kf, s_acc[nt], 0, 0, 0);
            }

        if (t + 1 < TILES) {
            int jn = jb + 64;
            kr0 = *(const short8*)(qkv + (size_t)(jn + row0) * TD + 768 + h * HD + cc0);
            kr1 = *(const short8*)(qkv + (size_t)(jn + row1) * TD + 768 + h * HD + cc1);
            vr0 = *(const short8*)(VtG + (size_t)(h * HD + row0) * NT + jn + cc0);
            vr1 = *(const short8*)(VtG + (size_t)(h * HD + row1) * NT + jn + cc1);
        }

        int r0 = wave * 16 + quad * 4;
        #pragma unroll
        for (int nt = 0; nt < 4; ++nt) {
            int jg = jb + nt * 16 + lm;
            int hj = jg / 48, wj = jg - hj * 48;
            short4_t bh4 = *(const short4_t*)(BhS + hj * 68 + r0);
            short4_t bw4 = *(const short4_t*)(BwS + wj * 68 + r0);
            #pragma unroll
            for (int r = 0; r < 4; ++r) {
                float b = h2f((unsigned short)bh4[r]) + h2f((unsigned short)bw4[r]);
                float pe = exp2f(fmaf(0.18033688f, s_acc[nt][r], b));
                lp4[r] += pe;
                Ps[(r0 + r) * 72 + nt * 16 + lm] = f2bf(pe);
            }
        }

        #pragma unroll
        for (int kt = 0; kt < 2; ++kt) {
            short8 pf = *(const short8*)(Ps + (wave * 16 + lm) * 72 + kt * 32 + quad * 8);
            #pragma unroll
            for (int nt = 0; nt < 4; ++nt) {
                short8 vf = *(const short8*)(Vts + (nt * 16 + lm) * 72 + kt * 32 + quad * 8);
                o_acc[nt] = __builtin_amdgcn_mfma_f32_16x16x32_bf16(
                    pf, vf, o_acc[nt], 0, 0, 0);
            }
        }
        __syncthreads();
    }

    #pragma unroll
    for (int r = 0; r < 4; ++r) {
        float s = lp4[r];
        s += __shfl_xor(s, 1, 16);
        s += __shfl_xor(s, 2, 16);
        s += __shfl_xor(s, 4, 16);
        s += __shfl_xor(s, 8, 16);
        if (lm == 0)
            Lpart[((size_t)z * NHEAD + h) * NT + i0 + wave * 16 + quad * 4 + r] = s;
    }
    unsigned short* op = Opart + (size_t)z * NT * DIM;
    #pragma unroll
    for (int nt = 0; nt < 4; ++nt)
        #pragma unroll
        for (int r = 0; r < 4; ++r)
            op[(size_t)(i0 + wave * 16 + quad * 4 + r) * DIM + h * HD + nt * 16 + lm]
                = f2bf(o_acc[nt][r]);
}

// ---------------------------------------------------------------------------
// Combine splits
// ---------------------------------------------------------------------------
__global__ __launch_bounds__(256)
void k_comb(const unsigned short* __restrict__ Opart, const float* __restrict__ Lpart,
            unsigned short* __restrict__ aob) {
    int gid = blockIdx.x * 256 + threadIdx.x;
    int t = gid / 96, c8 = (gid - t * 96) * 8;
    int h = c8 >> 6;
    float l = 0.f;
    #pragma unroll
    for (int s = 0; s < NSPLIT; ++s)
        l += Lpart[((size_t)s * NHEAD + h) * NT + t];
    float inv = 1.f / l;
    float acc[8] = {0, 0, 0, 0, 0, 0, 0, 0};
    #pragma unroll
    for (int s = 0; s < NSPLIT; ++s) {
        short8 v = *(const short8*)(Opart + (size_t)s * NT * DIM + (size_t)t * DIM + c8);
        #pragma unroll
        for (int i = 0; i < 8; ++i) acc[i] += bf2f((unsigned short)v[i]);
    }
    short8 o;
    #pragma unroll
    for (int i = 0; i < 8; ++i) o[i] = (short)f2bf(acc[i] * inv);
    *(short8*)(aob + (size_t)t * DIM + c8) = o;
}

// ---------------------------------------------------------------------------
extern "C" void kernel_launch(void* const* d_in, const int* in_sizes, int n_in,
                              void* d_out, int out_size, void* d_ws, size_t ws_size,
                              hipStream_t stream) {
    const float* x    = (const float*)d_in[0];
    const float* Wqkv = (const float*)d_in[1];
    const float* bqkv = (const float*)d_in[2];
    const float* Fu   = (const float*)d_in[3];
    const float* Fv   = (const float*)d_in[4];
    const float* qF   = (const float*)d_in[5];
    const float* vF   = (const float*)d_in[6];
    const float* rph  = (const float*)d_in[7];
    const float* rpw  = (const float*)d_in[8];
    const float* Wp   = (const float*)d_in[9];
    const float* bp   = (const float*)d_in[10];

    unsigned short* ws   = (unsigned short*)d_ws;
    unsigned short* qkvb = ws;                               // [2304][2304]
    unsigned short* aob  = qkvb;                             // alias: qkvb dead post-attn
    unsigned short* WpT  = qkvb + (size_t)NT * TD;           // [768][768]
    unsigned short* VtG  = WpT  + (size_t)DIM * DIM;         // [768][2304]
    unsigned short* BhG  = VtG  + (size_t)DIM * NT;          // [12][48][2304] half
    unsigned short* BwG  = BhG  + (size_t)NHEAD * 48 * NT;
    float*          Lpart = (float*)(BwG + (size_t)NHEAD * 48 * NT); // [4][12][2304]
    unsigned short* tail = (unsigned short*)(Lpart + (size_t)NSPLIT * NHEAD * NT);
    unsigned short* Ax   = tail;                             // [2304][832] (early)
    unsigned short* BqT  = Ax + (size_t)NT * KA;             // [2304][832] (early)
    unsigned short* Opart = tail;                            // [4][2304][768] (late)

    hipLaunchKernelGGL(k_prep, dim3(NT + 576 + 9), dim3(256), 0, stream,
                       x, Fu, qF, vF, Wqkv, Wp, Fv, Ax, BqT, WpT);
    hipLaunchKernelGGL((k_gemm64<128, 0, 1>), dim3(TD / 128, NT / 64), dim3(256), 0,
                       stream, Ax, BqT, bqkv, (void*)qkvb, TD, KA, VtG);
    hipLaunchKernelGGL(k_bias, dim3(48, NHEAD, 2), dim3(256), 0, stream,
                       qkvb, rph, rpw, BhG, BwG);
    hipLaunchKernelGGL(k_attn, dim3(NT / 64, NHEAD, NSPLIT), dim3(256), 0, stream,
                       qkvb, VtG, BhG, BwG, Opart, Lpart);
    hipLaunchKernelGGL(k_comb, dim3(NT * 96 / 256), dim3(256), 0, stream,
                       Opart, Lpart, aob);
    hipLaunchKernelGGL((k_gemm64<64, 1, 0>), dim3(DIM / 64, NT / 64), dim3(256), 0,
                       stream, aob, WpT, bp, d_out, DIM, DIM, (unsigned short*)nullptr);
}

// Round 10
// 194.971 us; speedup vs baseline: 1.4253x; 1.0448x over previous
//
#include <hip/hip_runtime.h>
#include <hip/hip_fp16.h>
#include <hip/hip_bf16.h>

#define NT    2304   // tokens = 48*48
#define DIM   768
#define TD    2304   // 3*dim
#define NHEAD 12
#define HD    64
#define RANK  32
#define KA    832    // augmented K = 768 + 32 (uq) + 32 (uv)
#define NSPLIT 4
#define TILES  9     // 36 / NSPLIT

typedef __attribute__((ext_vector_type(8))) short short8;
typedef __attribute__((ext_vector_type(4))) short short4_t;
typedef __attribute__((ext_vector_type(4))) float floatx4;

__device__ __forceinline__ unsigned short f2bf(float f) {
    union { float f; unsigned u; } v; v.f = f;
    unsigned u = v.u + 0x7FFFu + ((v.u >> 16) & 1u);
    return (unsigned short)(u >> 16);
}
__device__ __forceinline__ float bf2f(unsigned short h) {
    union { unsigned u; float f; } v; v.u = ((unsigned)h) << 16; return v.f;
}
__device__ __forceinline__ float h2f(unsigned short u) {
    __half h = *(__half*)&u; return __half2float(h);
}
__device__ __forceinline__ unsigned pkbf(float a, float b) {   // v_cvt_pk_bf16_f32
    __hip_bfloat162 t = __float22bfloat162_rn(make_float2(a, b));
    unsigned r; __builtin_memcpy(&r, &t, 4); return r;
}
__device__ __forceinline__ void async16(const unsigned short* g, unsigned short* l) {
    __builtin_amdgcn_global_load_lds(
        (const __attribute__((address_space(1))) unsigned int*)g,
        (__attribute__((address_space(3))) unsigned int*)l, 16, 0, 0);
}

// ---------------------------------------------------------------------------
// 64x64 fp32->bf16 transpose tile helper
// ---------------------------------------------------------------------------
__device__ __forceinline__ void tr_tile(const float* __restrict__ src,
                                        unsigned short* __restrict__ dst,
                                        int N, int P, int n0, int k0,
                                        unsigned short* tile, int tid) {
    #pragma unroll
    for (int p = 0; p < 4; ++p) {
        int krow = (tid >> 4) + p * 16, n4 = (tid & 15) * 4;
        float4 v = *(const float4*)(src + (size_t)(k0 + krow) * N + n0 + n4);
        tile[krow * 71 + n4 + 0] = f2bf(v.x);
        tile[krow * 71 + n4 + 1] = f2bf(v.y);
        tile[krow * 71 + n4 + 2] = f2bf(v.z);
        tile[krow * 71 + n4 + 3] = f2bf(v.w);
    }
    __syncthreads();
    #pragma unroll
    for (int p = 0; p < 2; ++p) {
        int c = tid + p * 256;
        int nrow = c >> 3, k8 = (c & 7) * 8;
        short8 o;
        #pragma unroll
        for (int i = 0; i < 8; ++i) o[i] = (short)tile[(k8 + i) * 71 + nrow];
        *(short8*)(dst + (size_t)(n0 + nrow) * P + k0 + k8) = o;
    }
}

// ---------------------------------------------------------------------------
// Fused prep: [0,2304) FacT rows; [2304,2736) Wqkv^T; [2736,2880) Wp^T;
// [2880,2889) Fv fill.
// ---------------------------------------------------------------------------
__global__ __launch_bounds__(256)
void k_prep(const float* __restrict__ x, const float* __restrict__ Fu,
            const float* __restrict__ qF, const float* __restrict__ vF,
            const float* __restrict__ Wqkv, const float* __restrict__ Wp,
            const float* __restrict__ Fv,
            unsigned short* __restrict__ Ax, unsigned short* __restrict__ BqT,
            unsigned short* __restrict__ WpT) {
    __shared__ __align__(16) unsigned short tile[64 * 71];
    int b = blockIdx.x;
    int tid = threadIdx.x;
    if (b < NT) {
        float* part = (float*)tile;            // [8][32]
        float* us = part + 256;                // [32]
        int row = b;
        int r = tid & 31, p = tid >> 5;
        const float* xr = x + (size_t)row * DIM;
        if (tid < 96) {                        // vectorized bf16 cast of x row
            const float4* pp = (const float4*)(xr + tid * 8);
            float4 a = pp[0], bb = pp[1];
            short8 o;
            o[0] = (short)f2bf(a.x);  o[1] = (short)f2bf(a.y);
            o[2] = (short)f2bf(a.z);  o[3] = (short)f2bf(a.w);
            o[4] = (short)f2bf(bb.x); o[5] = (short)f2bf(bb.y);
            o[6] = (short)f2bf(bb.z); o[7] = (short)f2bf(bb.w);
            *(short8*)(Ax + (size_t)row * KA + tid * 8) = o;
        }
        float acc = 0.f;
        int k0 = p * (DIM / 8);
        for (int k = k0; k < k0 + DIM / 8; ++k)
            acc = fmaf(xr[k], Fu[k * RANK + r], acc);
        part[p * 32 + r] = acc;
        __syncthreads();
        if (tid < 32) {
            float s = 0.f;
            #pragma unroll
            for (int pp2 = 0; pp2 < 8; ++pp2) s += part[pp2 * 32 + tid];
            us[tid] = s;
        }
        __syncthreads();
        if (tid < 64) {
            int c = tid & 31;
            const float* F = (tid < 32) ? qF : vF;
            float s = 0.f;
            #pragma unroll
            for (int rr = 0; rr < RANK; ++rr) s = fmaf(us[rr], F[rr * RANK + c], s);
            int col = (tid < 32) ? (768 + c) : (800 + c);
            Ax[(size_t)row * KA + col] = f2bf(s);
        }
    } else if (b < NT + 432) {
        int i = b - NT;
        tr_tile(Wqkv, BqT, TD, KA, (i % 36) * 64, (i / 36) * 64, tile, tid);
    } else if (b < NT + 576) {
        int i = b - NT - 432;
        tr_tile(Wp, WpT, DIM, DIM, (i % 12) * 64, (i / 12) * 64, tile, tid);
    } else {
        int i = b - NT - 576;
        int n = i * 256 + tid;
        unsigned short* d = BqT + (size_t)n * KA;
        #pragma unroll 4
        for (int r = 0; r < 32; ++r) {
            d[768 + r] = (n < 768)   ? f2bf(Fv[r * 768 + n])          : (unsigned short)0;
            d[800 + r] = (n >= 1536) ? f2bf(Fv[r * 768 + (n - 1536)]) : (unsigned short)0;
        }
    }
}

// ---------------------------------------------------------------------------
// bf16 MFMA GEMM, BM=64, BN in {64,128}: C = A @ BT^T + bias. BK=64.
// global_load_lds(16B) staging, XOR-8 swizzle on the global source.
// FUSEV: cols >=1536 also written transposed into VtG[chan][token].
// ---------------------------------------------------------------------------
template<int BN, int OUTF, int FUSEV>
__global__ __launch_bounds__(256)
void k_gemm64(const unsigned short* __restrict__ A,
              const unsigned short* __restrict__ BT,
              const float* __restrict__ bias, void* __restrict__ Cout,
              int N, int K, unsigned short* __restrict__ VtG) {
    __shared__ __align__(16) unsigned short As[64 * 64];
    __shared__ __align__(16) unsigned short Bs[BN * 64];
    constexpr int NJ = BN / 32;
    int tid = threadIdx.x;
    int m0 = blockIdx.y * 64, n0 = blockIdx.x * BN;
    int lane = tid & 63, wave = tid >> 6;
    int wr = wave >> 1, wc = wave & 1;
    int lm = lane & 15, quad = lane >> 4;

    int srow = tid >> 3;                         // 0..31
    int sgrp = ((tid & 7) ^ (srow & 7)) * 8;     // swizzled k-group (global src)
    const unsigned short* gA0 = A + (size_t)(m0 + srow) * K + sgrp;
    const unsigned short* gA1 = A + (size_t)(m0 + 32 + srow) * K + sgrp;
    const unsigned short* gB0 = BT + (size_t)(n0 + srow) * K + sgrp;
    const unsigned short* gB1 = BT + (size_t)(n0 + 32 + srow) * K + sgrp;
    unsigned short* lA0 = As + wave * 512;       // wave-uniform bases
    unsigned short* lA1 = As + 2048 + wave * 512;
    unsigned short* lB0 = Bs + wave * 512;
    unsigned short* lB1 = Bs + 2048 + wave * 512;

    floatx4 acc[2][NJ];
    #pragma unroll
    for (int i = 0; i < 2; ++i)
        #pragma unroll
        for (int j = 0; j < NJ; ++j) acc[i][j] = (floatx4){0.f, 0.f, 0.f, 0.f};

    for (int kt = 0; kt < K; kt += 64) {
        async16(gA0 + kt, lA0);
        async16(gA1 + kt, lA1);
        async16(gB0 + kt, lB0);
        async16(gB1 + kt, lB1);
        if constexpr (BN == 128) {
            const unsigned short* gB2 = BT + (size_t)(n0 + 64 + srow) * K + sgrp;
            const unsigned short* gB3 = BT + (size_t)(n0 + 96 + srow) * K + sgrp;
            async16(gB2 + kt, Bs + 4096 + wave * 512);
            async16(gB3 + kt, Bs + 6144 + wave * 512);
        }
        __syncthreads();
        #pragma unroll
        for (int kk = 0; kk < 2; ++kk) {
            short8 af[2];
            #pragma unroll
            for (int t2 = 0; t2 < 2; ++t2) {
                int row = wr * 32 + t2 * 16 + lm;
                int g = kk * 4 + quad;
                af[t2] = *(const short8*)(As + row * 64 + ((g ^ (row & 7)) * 8));
            }
            #pragma unroll
            for (int j = 0; j < NJ; ++j) {
                int row = wc * (BN / 2) + j * 16 + lm;
                int g = kk * 4 + quad;
                short8 bq = *(const short8*)(Bs + row * 64 + ((g ^ (row & 7)) * 8));
                acc[0][j] = __builtin_amdgcn_mfma_f32_16x16x32_bf16(af[0], bq, acc[0][j], 0, 0, 0);
                acc[1][j] = __builtin_amdgcn_mfma_f32_16x16x32_bf16(af[1], bq, acc[1][j], 0, 0, 0);
            }
        }
        __syncthreads();
    }

    #pragma unroll
    for (int jt = 0; jt < NJ; ++jt) {
        int col = n0 + wc * (BN / 2) + jt * 16 + lm;
        float bv = bias[col];
        #pragma unroll
        for (int it = 0; it < 2; ++it) {
            int rowb = m0 + wr * 32 + it * 16 + quad * 4;
            #pragma unroll
            for (int r = 0; r < 4; ++r) {
                float val = acc[it][jt][r] + bv;
                if (OUTF)
                    ((float*)Cout)[(size_t)(rowb + r) * N + col] = val;
                else
                    ((unsigned short*)Cout)[(size_t)(rowb + r) * N + col] = f2bf(val);
            }
            if (FUSEV && col >= 1536) {
                short4_t vt;
                #pragma unroll
                for (int r = 0; r < 4; ++r) vt[r] = (short)f2bf(acc[it][jt][r] + bv);
                *(short4_t*)(VtG + (size_t)(col - 1536) * NT + rowb) = vt;
            }
        }
    }
}

// ---------------------------------------------------------------------------
// Rel-pos bias tables via MFMA. Stored as half, pre-multiplied by log2(e).
//   which=0: BhG[h][j][t]   (j = key h-coord)
//   which=1: BwT[h][t][j]   (j = key w-coord)  -- TRANSPOSED layout
// ---------------------------------------------------------------------------
__global__ __launch_bounds__(256)
void k_bias(const unsigned short* __restrict__ qkv, const float* __restrict__ rph,
            const float* __restrict__ rpw, unsigned short* __restrict__ BhG,
            unsigned short* __restrict__ BwT) {
    __shared__ __align__(16) unsigned short Qs[48 * 68];
    __shared__ __align__(16) unsigned short Ts[48 * 68];
    int tid = threadIdx.x;
    int pos = blockIdx.x, h = blockIdx.y, which = blockIdx.z;
    const float* tab = which ? rpw : rph;
    for (int idx = tid; idx < 48 * 8; idx += 256) {
        int row = idx >> 3, c8 = (idx & 7) * 8;
        int t = which ? (row * 48 + pos) : (pos * 48 + row);
        *(short8*)(Qs + row * 68 + c8) =
            *(const short8*)(qkv + (size_t)t * TD + h * HD + c8);
    }
    for (int idx = tid; idx < 48 * 8; idx += 256) {
        int j = idx >> 3, c8 = (idx & 7) * 8;
        const float* src = tab + (size_t)(pos + 47 - j) * HD + c8;
        short8 o;
        #pragma unroll
        for (int i = 0; i < 8; ++i) o[i] = (short)f2bf(src[i]);
        *(short8*)(Ts + j * 68 + c8) = o;
    }
    __syncthreads();
    int lane = tid & 63, wave = tid >> 6;
    int lm = lane & 15, quad = lane >> 4;
    for (int tt = wave; tt < 9; tt += 4) {
        int rt = tt / 3, jt = tt - rt * 3;
        floatx4 acc = (floatx4){0.f, 0.f, 0.f, 0.f};
        #pragma unroll
        for (int kt = 0; kt < 2; ++kt) {
            short8 a = *(const short8*)(Qs + (rt * 16 + lm) * 68 + kt * 32 + quad * 8);
            short8 bb = *(const short8*)(Ts + (jt * 16 + lm) * 68 + kt * 32 + quad * 8);
            acc = __builtin_amdgcn_mfma_f32_16x16x32_bf16(a, bb, acc, 0, 0, 0);
        }
        int j = jt * 16 + lm;
        int r0 = rt * 16 + quad * 4;
        if (which == 0) {
            short4_t o;
            #pragma unroll
            for (int r = 0; r < 4; ++r) {
                __half hh = __float2half(acc[r] * 1.44269504f);
                o[r] = *(short*)&hh;
            }
            *(short4_t*)(BhG + (size_t)(h * 48 + j) * NT + pos * 48 + r0) = o;
        } else {
            #pragma unroll
            for (int r = 0; r < 4; ++r) {
                __half hh = __float2half(acc[r] * 1.44269504f);
                int t = (r0 + r) * 48 + pos;
                BwT[((size_t)h * NT + t) * 48 + j] = *(unsigned short*)&hh;
            }
        }
    }
}

// ---------------------------------------------------------------------------
// MFMA flash attention, 4-way key split, S^T layout:
// S^T = K·Q^T via operand swap -> lane holds 4 CONSECUTIVE KEYS for one q-row:
// Ps writes become b64, bias = 1 scalar + 1 b64, row-sum = 2 shfl_xor.
// ---------------------------------------------------------------------------
__global__ __launch_bounds__(256)
void k_attn(const unsigned short* __restrict__ qkv,
            const unsigned short* __restrict__ VtG,
            const unsigned short* __restrict__ BhG,
            const unsigned short* __restrict__ BwT,
            unsigned short* __restrict__ Opart, float* __restrict__ Lpart) {
    __shared__ __align__(16) unsigned short Ks[64 * 72];   // K [key][chan]
    __shared__ __align__(16) unsigned short Vts[64 * 72];  // V^T [chan][key]
    __shared__ __align__(16) unsigned short Ps[64 * 72];   // Q stage, then P [qrow][key]
    __shared__ __align__(16) unsigned short BhS[48 * 64];  // half*log2e [hj][qrow]
    __shared__ __align__(16) unsigned short BwS[64 * 56];  // half*log2e [qrow][wj]

    int tid = threadIdx.x;
    int lane = tid & 63, wave = tid >> 6;
    int lm = lane & 15, quad = lane >> 4;
    int i0 = blockIdx.x * 64, h = blockIdx.y, z = blockIdx.z;

    int row0 = tid >> 3, cc0 = (tid & 7) * 8;
    int row1 = row0 + 32, cc1 = cc0;

    *(short8*)(Ps + row0 * 72 + cc0) =
        *(const short8*)(qkv + (size_t)(i0 + row0) * TD + h * HD + cc0);
    *(short8*)(Ps + row1 * 72 + cc1) =
        *(const short8*)(qkv + (size_t)(i0 + row1) * TD + h * HD + cc1);
    __syncthreads();
    short8 qf[2];
    qf[0] = *(const short8*)(Ps + (wave * 16 + lm) * 72 + quad * 8);
    qf[1] = *(const short8*)(Ps + (wave * 16 + lm) * 72 + 32 + quad * 8);

    // stage bias tables: BhS[hj][qrow] (b64 copies), BwS[qrow][wj] (b128 copies)
    for (int idx = tid; idx < 48 * 16; idx += 256) {
        int j = idx >> 4, r4 = (idx & 15) * 4;
        *(short4_t*)(BhS + j * 64 + r4) =
            *(const short4_t*)(BhG + (size_t)(h * 48 + j) * NT + i0 + r4);
    }
    for (int idx = tid; idx < 64 * 6; idx += 256) {
        int row = idx / 6, c8 = (idx - row * 6) * 8;
        *(short8*)(BwS + row * 56 + c8) =
            *(const short8*)(BwT + ((size_t)h * NT + i0 + row) * 48 + c8);
    }

    int j0 = z * TILES * 64;
    short8 kr0 = *(const short8*)(qkv + (size_t)(j0 + row0) * TD + 768 + h * HD + cc0);
    short8 kr1 = *(const short8*)(qkv + (size_t)(j0 + row1) * TD + 768 + h * HD + cc1);
    short8 vr0 = *(const short8*)(VtG + (size_t)(h * HD + row0) * NT + j0 + cc0);
    short8 vr1 = *(const short8*)(VtG + (size_t)(h * HD + row1) * NT + j0 + cc1);

    floatx4 o_acc[4];
    float lp = 0.f;
    #pragma unroll
    for (int nt = 0; nt < 4; ++nt) o_acc[nt] = (floatx4){0.f, 0.f, 0.f, 0.f};

    int qrow = wave * 16 + lm;                 // this lane's q-row (local)

    for (int t = 0; t < TILES; ++t) {
        int jb = j0 + t * 64;
        *(short8*)(Ks + row0 * 72 + cc0) = kr0;
        *(short8*)(Ks + row1 * 72 + cc1) = kr1;
        *(short8*)(Vts + row0 * 72 + cc0) = vr0;
        *(short8*)(Vts + row1 * 72 + cc1) = vr1;
        __syncthreads();

        // S^T = K Q^T  (A = K-frag, B = Q-frag)
        floatx4 s_acc[4];
        #pragma unroll
        for (int nt = 0; nt < 4; ++nt) s_acc[nt] = (floatx4){0.f, 0.f, 0.f, 0.f};
        #pragma unroll
        for (int kt = 0; kt < 2; ++kt)
            #pragma unroll
            for (int nt = 0; nt < 4; ++nt) {
                short8 kf = *(const short8*)(Ks + (nt * 16 + lm) * 72 + kt * 32 + quad * 8);
                s_acc[nt] = __builtin_amdgcn_mfma_f32_16x16x32_bf16(
                    kf, qf[kt], s_acc[nt], 0, 0, 0);
            }

        if (t + 1 < TILES) {
            int jn = jb + 64;
            kr0 = *(const short8*)(qkv + (size_t)(jn + row0) * TD + 768 + h * HD + cc0);
            kr1 = *(const short8*)(qkv + (size_t)(jn + row1) * TD + 768 + h * HD + cc1);
            vr0 = *(const short8*)(VtG + (size_t)(h * HD + row0) * NT + jn + cc0);
            vr1 = *(const short8*)(VtG + (size_t)(h * HD + row1) * NT + jn + cc1);
        }

        // epilogue: lane owns keys nt*16+quad*4..+3 for its single q-row
        #pragma unroll
        for (int nt = 0; nt < 4; ++nt) {
            int lk = nt * 16 + quad * 4;       // local key base
            int jg = jb + lk;                  // global key base (4-aligned)
            int hj = jg / 48, wj0 = jg - hj * 48;   // hj const over the 4
            float bh = h2f(BhS[hj * 64 + qrow]);
            short4_t bw4 = *(const short4_t*)(BwS + qrow * 56 + wj0);
            float pe[4];
            #pragma unroll
            for (int r = 0; r < 4; ++r) {
                float b = bh + h2f((unsigned short)bw4[r]);
                pe[r] = exp2f(fmaf(0.18033688f, s_acc[nt][r], b));
                lp += pe[r];
            }
            union { unsigned u[2]; short4_t s; } pk;
            pk.u[0] = pkbf(pe[0], pe[1]);
            pk.u[1] = pkbf(pe[2], pe[3]);
            *(short4_t*)(Ps + qrow * 72 + lk) = pk.s;
        }

        // O += P V : pf from wave-private Ps rows, vf from Vts
        #pragma unroll
        for (int kt = 0; kt < 2; ++kt) {
            short8 pf = *(const short8*)(Ps + qrow * 72 + kt * 32 + quad * 8);
            #pragma unroll
            for (int nt = 0; nt < 4; ++nt) {
                short8 vf = *(const short8*)(Vts + (nt * 16 + lm) * 72 + kt * 32 + quad * 8);
                o_acc[nt] = __builtin_amdgcn_mfma_f32_16x16x32_bf16(
                    pf, vf, o_acc[nt], 0, 0, 0);
            }
        }
        __syncthreads();
    }

    // row sums: lane holds partial for its q-row over its quad's keys
    lp += __shfl_xor(lp, 16);
    lp += __shfl_xor(lp, 32);
    if (quad == 0)
        Lpart[((size_t)z * NHEAD + h) * NT + i0 + qrow] = lp;

    unsigned short* op = Opart + (size_t)z * NT * DIM;
    #pragma unroll
    for (int nt = 0; nt < 4; ++nt)
        #pragma unroll
        for (int r = 0; r < 4; ++r)
            op[(size_t)(i0 + wave * 16 + quad * 4 + r) * DIM + h * HD + nt * 16 + lm]
                = f2bf(o_acc[nt][r]);
}

// ---------------------------------------------------------------------------
// Combine splits
// ---------------------------------------------------------------------------
__global__ __launch_bounds__(256)
void k_comb(const unsigned short* __restrict__ Opart, const float* __restrict__ Lpart,
            unsigned short* __restrict__ aob) {
    int gid = blockIdx.x * 256 + threadIdx.x;
    int t = gid / 96, c8 = (gid - t * 96) * 8;
    int h = c8 >> 6;
    float l = 0.f;
    #pragma unroll
    for (int s = 0; s < NSPLIT; ++s)
        l += Lpart[((size_t)s * NHEAD + h) * NT + t];
    float inv = 1.f / l;
    float acc[8] = {0, 0, 0, 0, 0, 0, 0, 0};
    #pragma unroll
    for (int s = 0; s < NSPLIT; ++s) {
        short8 v = *(const short8*)(Opart + (size_t)s * NT * DIM + (size_t)t * DIM + c8);
        #pragma unroll
        for (int i = 0; i < 8; ++i) acc[i] += bf2f((unsigned short)v[i]);
    }
    union { unsigned u[4]; short8 s; } o;
    #pragma unroll
    for (int i = 0; i < 4; ++i) o.u[i] = pkbf(acc[2 * i] * inv, acc[2 * i + 1] * inv);
    *(short8*)(aob + (size_t)t * DIM + c8) = o.s;
}

// ---------------------------------------------------------------------------
extern "C" void kernel_launch(void* const* d_in, const int* in_sizes, int n_in,
                              void* d_out, int out_size, void* d_ws, size_t ws_size,
                              hipStream_t stream) {
    const float* x    = (const float*)d_in[0];
    const float* Wqkv = (const float*)d_in[1];
    const float* bqkv = (const float*)d_in[2];
    const float* Fu   = (const float*)d_in[3];
    const float* Fv   = (const float*)d_in[4];
    const float* qF   = (const float*)d_in[5];
    const float* vF   = (const float*)d_in[6];
    const float* rph  = (const float*)d_in[7];
    const float* rpw  = (const float*)d_in[8];
    const float* Wp   = (const float*)d_in[9];
    const float* bp   = (const float*)d_in[10];

    unsigned short* ws   = (unsigned short*)d_ws;
    unsigned short* qkvb = ws;                               // [2304][2304]
    unsigned short* aob  = qkvb;                             // alias: qkvb dead post-attn
    unsigned short* WpT  = qkvb + (size_t)NT * TD;           // [768][768]
    unsigned short* VtG  = WpT  + (size_t)DIM * DIM;         // [768][2304]
    unsigned short* BhG  = VtG  + (size_t)DIM * NT;          // [12][48][2304] half
    unsigned short* BwT  = BhG  + (size_t)NHEAD * 48 * NT;   // [12][2304][48] half
    float*          Lpart = (float*)(BwT + (size_t)NHEAD * NT * 48); // [4][12][2304]
    unsigned short* tail = (unsigned short*)(Lpart + (size_t)NSPLIT * NHEAD * NT);
    unsigned short* Ax   = tail;                             // [2304][832] (early)
    unsigned short* BqT  = Ax + (size_t)NT * KA;             // [2304][832] (early)
    unsigned short* Opart = tail;                            // [4][2304][768] (late)

    hipLaunchKernelGGL(k_prep, dim3(NT + 576 + 9), dim3(256), 0, stream,
                       x, Fu, qF, vF, Wqkv, Wp, Fv, Ax, BqT, WpT);
    hipLaunchKernelGGL((k_gemm64<128, 0, 1>), dim3(TD / 128, NT / 64), dim3(256), 0,
                       stream, Ax, BqT, bqkv, (void*)qkvb, TD, KA, VtG);
    hipLaunchKernelGGL(k_bias, dim3(48, NHEAD, 2), dim3(256), 0, stream,
                       qkvb, rph, rpw, BhG, BwT);
    hipLaunchKernelGGL(k_attn, dim3(NT / 64, NHEAD, NSPLIT), dim3(256), 0, stream,
                       qkvb, VtG, BhG, BwT, Opart, Lpart);
    hipLaunchKernelGGL(k_comb, dim3(NT * 96 / 256), dim3(256), 0, stream,
                       Opart, Lpart, aob);
    hipLaunchKernelGGL((k_gemm64<64, 1, 0>), dim3(DIM / 64, NT / 64), dim3(256), 0,
                       stream, aob, WpT, bp, d_out, DIM, DIM, (unsigned short*)nullptr);
}